// Round 1
// baseline (423.574 us; speedup 1.0000x reference)
//
#include <hip/hip_runtime.h>

typedef __bf16 bf16x8 __attribute__((ext_vector_type(8)));
typedef __bf16 bf16x4 __attribute__((ext_vector_type(4)));
typedef float  f32x4  __attribute__((ext_vector_type(4)));

#define HPAD 68  // bf16 elems per LDS row (136 B): breaks power-of-2 bank aliasing on scatter writes
#define LDS_WAIT() asm volatile("s_waitcnt lgkmcnt(0)" ::: "memory")

static __device__ __forceinline__ bf16x8 ld_frag_lds(const __bf16* p) {
    bf16x4 lo = *(const bf16x4*)p;        // 8B-aligned -> ds_read_b64
    bf16x4 hi = *(const bf16x4*)(p + 4);
    bf16x8 r;
    r[0] = lo[0]; r[1] = lo[1]; r[2] = lo[2]; r[3] = lo[3];
    r[4] = hi[0]; r[5] = hi[1]; r[6] = hi[2]; r[7] = hi[3];
    return r;
}

static __device__ __forceinline__ bf16x8 ld_frag_g(const float* p) {
    float4 v0 = ((const float4*)p)[0];
    float4 v1 = ((const float4*)p)[1];
    bf16x8 r;
    r[0] = (__bf16)v0.x; r[1] = (__bf16)v0.y; r[2] = (__bf16)v0.z; r[3] = (__bf16)v0.w;
    r[4] = (__bf16)v1.x; r[5] = (__bf16)v1.y; r[6] = (__bf16)v1.z; r[7] = (__bf16)v1.w;
    return r;
}

// ReLU(acc + b) -> LayerNorm(*g + be) -> bf16 into LDS tile (C-layout scatter).
static __device__ __forceinline__ void ln_epilogue(const f32x4* acc, const float* bv,
                                                   const float* gv, const float* ev,
                                                   __bf16* hp, int n16, int q) {
    float u[4][4];
    float sm[4] = {0.f, 0.f, 0.f, 0.f};
    float sq[4] = {0.f, 0.f, 0.f, 0.f};
#pragma unroll
    for (int t = 0; t < 4; ++t)
#pragma unroll
        for (int j = 0; j < 4; ++j) {
            float x = acc[t][j] + bv[t];
            x = fmaxf(x, 0.0f);
            u[t][j] = x;
            sm[j] += x;
            sq[j] += x * x;
        }
#pragma unroll
    for (int msk = 1; msk <= 8; msk <<= 1)
#pragma unroll
        for (int j = 0; j < 4; ++j) {
            sm[j] += __shfl_xor(sm[j], msk, 64);
            sq[j] += __shfl_xor(sq[j], msk, 64);
        }
    float mean[4], rstd[4];
#pragma unroll
    for (int j = 0; j < 4; ++j) {
        mean[j] = sm[j] * 0.015625f;
        float v = sq[j] * 0.015625f - mean[j] * mean[j];
        rstd[j] = rsqrtf(fmaxf(v, 0.0f) + 1e-5f);
    }
#pragma unroll
    for (int t = 0; t < 4; ++t)
#pragma unroll
        for (int j = 0; j < 4; ++j) {
            float y = (u[t][j] - mean[j]) * rstd[j] * gv[t] + ev[t];
            hp[(q * 4 + j) * HPAD + t * 16 + n16] = (__bf16)y;
        }
}

__global__ __launch_bounds__(256, 2)
void edge_model_kernel(const float* __restrict__ srcp,
                       const float* __restrict__ dstp,
                       const float* __restrict__ eap,
                       const float* __restrict__ W1, const float* __restrict__ b1,
                       const float* __restrict__ g1, const float* __restrict__ be1,
                       const float* __restrict__ W2, const float* __restrict__ b2,
                       const float* __restrict__ g2, const float* __restrict__ be2,
                       const float* __restrict__ W3, const float* __restrict__ b3,
                       float* __restrict__ out, int E) {
    __shared__ alignas(16) __bf16 hs[4][2][16 * HPAD];  // per-wave h1/h2 scratch

    const int tid = threadIdx.x;
    const int w   = tid >> 6;   // wave in block
    const int l   = tid & 63;   // lane
    const int n16 = l & 15;
    const int q   = l >> 4;

    // ---- B-operand weight fragments, held in registers for the whole kernel ----
    // B layout: lane holds B[k = 8*q + j][n = n16] for each 16-wide N tile.
    bf16x8 w1f[3][4];  // K=96 (3 ksteps) x N=64 (4 ntiles)
    bf16x8 w2f[5][4];  // K=160 x N=64
    bf16x8 w3f[2][2];  // K=64 x N=32
#pragma unroll
    for (int s = 0; s < 3; ++s)
#pragma unroll
        for (int t = 0; t < 4; ++t) {
            bf16x8 f;
#pragma unroll
            for (int jj = 0; jj < 8; ++jj)
                f[jj] = (__bf16)W1[(s * 32 + q * 8 + jj) * 64 + t * 16 + n16];
            w1f[s][t] = f;
        }
#pragma unroll
    for (int s = 0; s < 5; ++s)
#pragma unroll
        for (int t = 0; t < 4; ++t) {
            bf16x8 f;
#pragma unroll
            for (int jj = 0; jj < 8; ++jj)
                f[jj] = (__bf16)W2[(s * 32 + q * 8 + jj) * 64 + t * 16 + n16];
            w2f[s][t] = f;
        }
#pragma unroll
    for (int s = 0; s < 2; ++s)
#pragma unroll
        for (int t = 0; t < 2; ++t) {
            bf16x8 f;
#pragma unroll
            for (int jj = 0; jj < 8; ++jj)
                f[jj] = (__bf16)W3[(s * 32 + q * 8 + jj) * 32 + t * 16 + n16];
            w3f[s][t] = f;
        }

    // per-lane affine params (channel c = t*16 + n16 in C-layout)
    float b1v[4], g1v[4], e1v[4], b2v[4], g2v[4], e2v[4], b3v[2];
#pragma unroll
    for (int t = 0; t < 4; ++t) {
        int c = t * 16 + n16;
        b1v[t] = b1[c]; g1v[t] = g1[c]; e1v[t] = be1[c];
        b2v[t] = b2[c]; g2v[t] = g2[c]; e2v[t] = be2[c];
    }
    b3v[0] = b3[n16];
    b3v[1] = b3[16 + n16];

    const int nTiles = (E + 15) >> 4;
    const int stride = gridDim.x * 4;
    __bf16* h1p = &hs[w][0][0];
    __bf16* h2p = &hs[w][1][0];

    for (int tile = blockIdx.x * 4 + w; tile < nTiles; tile += stride) {
        const int e0 = tile << 4;
        const int rr = min(e0 + n16, E - 1);
        const size_t abase = (size_t)rr * 32 + q * 8;

        // x0 A-fragments: kstep0=src, kstep1=dest, kstep2=edge_attr (reused in GEMM2)
        bf16x8 a0[3];
        a0[0] = ld_frag_g(srcp + abase);
        a0[1] = ld_frag_g(dstp + abase);
        a0[2] = ld_frag_g(eap + abase);

        // ---- GEMM1: [16x96] @ [96x64] ----
        f32x4 acc1[4] = {};
#pragma unroll
        for (int s = 0; s < 3; ++s)
#pragma unroll
            for (int t = 0; t < 4; ++t)
                acc1[t] = __builtin_amdgcn_mfma_f32_16x16x32_bf16(a0[s], w1f[s][t], acc1[t], 0, 0, 0);

        ln_epilogue(acc1, b1v, g1v, e1v, h1p, n16, q);
        LDS_WAIT();

        // ---- GEMM2: [16x160] @ [160x64], A = [h1 | x0] ----
        f32x4 acc2[4] = {};
        bf16x8 h1f0 = ld_frag_lds(h1p + n16 * HPAD + q * 8);
        bf16x8 h1f1 = ld_frag_lds(h1p + n16 * HPAD + 32 + q * 8);
#pragma unroll
        for (int t = 0; t < 4; ++t)
            acc2[t] = __builtin_amdgcn_mfma_f32_16x16x32_bf16(h1f0, w2f[0][t], acc2[t], 0, 0, 0);
#pragma unroll
        for (int t = 0; t < 4; ++t)
            acc2[t] = __builtin_amdgcn_mfma_f32_16x16x32_bf16(h1f1, w2f[1][t], acc2[t], 0, 0, 0);
#pragma unroll
        for (int s = 0; s < 3; ++s)
#pragma unroll
            for (int t = 0; t < 4; ++t)
                acc2[t] = __builtin_amdgcn_mfma_f32_16x16x32_bf16(a0[s], w2f[2 + s][t], acc2[t], 0, 0, 0);

        ln_epilogue(acc2, b2v, g2v, e2v, h2p, n16, q);
        LDS_WAIT();

        // ---- GEMM3: [16x64] @ [64x32] + b3 ----
        f32x4 acc3[2] = {};
#pragma unroll
        for (int s = 0; s < 2; ++s) {
            bf16x8 h2f = ld_frag_lds(h2p + n16 * HPAD + s * 32 + q * 8);
#pragma unroll
            for (int t = 0; t < 2; ++t)
                acc3[t] = __builtin_amdgcn_mfma_f32_16x16x32_bf16(h2f, w3f[s][t], acc3[t], 0, 0, 0);
        }

        // store: lane holds out[e0 + 4q + j][t*16 + n16]; 16-lane groups write 64B segments
#pragma unroll
        for (int t = 0; t < 2; ++t)
#pragma unroll
            for (int j = 0; j < 4; ++j) {
                int r = e0 + q * 4 + j;
                if (r < E) out[(size_t)r * 32 + t * 16 + n16] = acc3[t][j] + b3v[t];
            }
    }
}

extern "C" void kernel_launch(void* const* d_in, const int* in_sizes, int n_in,
                              void* d_out, int out_size, void* d_ws, size_t ws_size,
                              hipStream_t stream) {
    (void)n_in; (void)out_size; (void)d_ws; (void)ws_size;
    const float* srcp = (const float*)d_in[0];
    const float* dstp = (const float*)d_in[1];
    const float* eap  = (const float*)d_in[2];
    const float* W1   = (const float*)d_in[3];
    const float* b1   = (const float*)d_in[4];
    const float* g1   = (const float*)d_in[5];
    const float* be1  = (const float*)d_in[6];
    const float* W2   = (const float*)d_in[7];
    const float* b2   = (const float*)d_in[8];
    const float* g2   = (const float*)d_in[9];
    const float* be2  = (const float*)d_in[10];
    const float* W3   = (const float*)d_in[11];
    const float* b3   = (const float*)d_in[12];
    float* out = (float*)d_out;

    const int E = in_sizes[0] / 32;
    const int nTiles = (E + 15) / 16;
    int blocks = (nTiles + 3) / 4;
    if (blocks > 512) blocks = 512;  // 2 blocks/CU at <=256 VGPR, 8 waves/CU

    edge_model_kernel<<<blocks, 256, 0, stream>>>(srcp, dstp, eap, W1, b1, g1, be1,
                                                  W2, b2, g2, be2, W3, b3, out, E);
}

// Round 2
// 408.982 us; speedup vs baseline: 1.0357x; 1.0357x over previous
//
#include <hip/hip_runtime.h>

typedef __bf16 bf16x8 __attribute__((ext_vector_type(8)));
typedef __bf16 bf16x4 __attribute__((ext_vector_type(4)));
typedef float  f32x4  __attribute__((ext_vector_type(4)));

#define NW 8       // waves per block
#define HPAD 68    // bf16 elems per LDS h-row (136 B); measured 0 bank conflicts
#define NFRAG 36   // 12 (W1) + 20 (W2) + 4 (W3) fragment tiles
#define LDS_WAIT() asm volatile("s_waitcnt lgkmcnt(0)" ::: "memory")

static __device__ __forceinline__ bf16x8 ld_frag_lds8(const __bf16* p) {
    bf16x4 lo = *(const bf16x4*)p;
    bf16x4 hi = *(const bf16x4*)(p + 4);
    bf16x8 r;
    r[0] = lo[0]; r[1] = lo[1]; r[2] = lo[2]; r[3] = lo[3];
    r[4] = hi[0]; r[5] = hi[1]; r[6] = hi[2]; r[7] = hi[3];
    return r;
}

static __device__ __forceinline__ bf16x8 cvt_frag(float4 v0, float4 v1) {
    bf16x8 r;
    r[0] = (__bf16)v0.x; r[1] = (__bf16)v0.y; r[2] = (__bf16)v0.z; r[3] = (__bf16)v0.w;
    r[4] = (__bf16)v1.x; r[5] = (__bf16)v1.y; r[6] = (__bf16)v1.z; r[7] = (__bf16)v1.w;
    return r;
}

// ReLU(acc + b) -> LayerNorm(*g, +be) -> bf16 scatter into per-wave LDS tile (C-layout).
static __device__ __forceinline__ void ln_epilogue(const f32x4* acc, const float* bv,
                                                   const float* gv, const float* ev,
                                                   __bf16* hp, int n16, int q) {
    float u[4][4];
    float sm[4] = {0.f, 0.f, 0.f, 0.f};
    float sq[4] = {0.f, 0.f, 0.f, 0.f};
#pragma unroll
    for (int t = 0; t < 4; ++t)
#pragma unroll
        for (int j = 0; j < 4; ++j) {
            float x = acc[t][j] + bv[t];
            x = fmaxf(x, 0.0f);
            u[t][j] = x;
            sm[j] += x;
            sq[j] += x * x;
        }
#pragma unroll
    for (int msk = 1; msk <= 8; msk <<= 1)
#pragma unroll
        for (int j = 0; j < 4; ++j) {
            sm[j] += __shfl_xor(sm[j], msk, 64);
            sq[j] += __shfl_xor(sq[j], msk, 64);
        }
    float mean[4], rstd[4];
#pragma unroll
    for (int j = 0; j < 4; ++j) {
        mean[j] = sm[j] * 0.015625f;
        float v = sq[j] * 0.015625f - mean[j] * mean[j];
        rstd[j] = rsqrtf(fmaxf(v, 0.0f) + 1e-5f);
    }
#pragma unroll
    for (int t = 0; t < 4; ++t)
#pragma unroll
        for (int j = 0; j < 4; ++j) {
            float y = (u[t][j] - mean[j]) * rstd[j] * gv[t] + ev[t];
            hp[(q * 4 + j) * HPAD + t * 16 + n16] = (__bf16)y;
        }
}

__global__ __launch_bounds__(512, 4)
void edge_model_kernel(const float* __restrict__ srcp,
                       const float* __restrict__ dstp,
                       const float* __restrict__ eap,
                       const float* __restrict__ W1, const float* __restrict__ b1,
                       const float* __restrict__ g1, const float* __restrict__ be1,
                       const float* __restrict__ W2, const float* __restrict__ b2,
                       const float* __restrict__ g2, const float* __restrict__ be2,
                       const float* __restrict__ W3, const float* __restrict__ b3,
                       float* __restrict__ out, int E) {
    // Weight fragments, fragment-contiguous: fragment fid, lane l -> wlds[fid*512 + l*8 .. +8)
    __shared__ alignas(16) __bf16 wlds[NFRAG * 64 * 8];        // 36,864 B
    __shared__ alignas(16) __bf16 hs[NW][2][16 * HPAD];        // 34,816 B

    const int tid = threadIdx.x;
    const int w   = tid >> 6;
    const int l   = tid & 63;
    const int n16 = l & 15;
    const int q   = l >> 4;

    // ---- cooperative fill of weight fragments (once per block) ----
    for (int idx = tid; idx < NFRAG * 64; idx += blockDim.x) {
        int fid = idx >> 6, fl = idx & 63;
        int lq = fl >> 4, ln = fl & 15;
        const float* Wsrc; int ldw, row0, col;
        if (fid < 12)      { int s = fid >> 2,        t = fid & 3;        Wsrc = W1; ldw = 64; row0 = s * 32 + lq * 8; col = t * 16 + ln; }
        else if (fid < 32) { int f = fid - 12, s = f >> 2, t = f & 3;     Wsrc = W2; ldw = 64; row0 = s * 32 + lq * 8; col = t * 16 + ln; }
        else               { int f = fid - 32, s = f >> 1, t = f & 1;     Wsrc = W3; ldw = 32; row0 = s * 32 + lq * 8; col = t * 16 + ln; }
        __bf16* dst = wlds + idx * 8;
#pragma unroll
        for (int jj = 0; jj < 8; ++jj)
            dst[jj] = (__bf16)Wsrc[(row0 + jj) * ldw + col];
    }

    // per-lane affine params (channel c = t*16 + n16 in C-layout)
    float b1v[4], g1v[4], e1v[4], b2v[4], g2v[4], e2v[4], b3v[2];
#pragma unroll
    for (int t = 0; t < 4; ++t) {
        int c = t * 16 + n16;
        b1v[t] = b1[c]; g1v[t] = g1[c]; e1v[t] = be1[c];
        b2v[t] = b2[c]; g2v[t] = g2[c]; e2v[t] = be2[c];
    }
    b3v[0] = b3[n16];
    b3v[1] = b3[16 + n16];

    __syncthreads();   // weights visible to all waves; no block barriers after this

    const int nTiles = (E + 15) >> 4;
    const int stride = gridDim.x * NW;
    __bf16* h1p = &hs[w][0][0];
    __bf16* h2p = &hs[w][1][0];
    const __bf16* wl = wlds + l * 8;   // lane-local base; fragment fid at wl + fid*512

    int tile = blockIdx.x * NW + w;
    if (tile >= nTiles) return;

    // first tile's x0 fragments
    bf16x8 a0[3];
    {
        const size_t abase = (size_t)min((tile << 4) + n16, E - 1) * 32 + q * 8;
        a0[0] = cvt_frag(((const float4*)(srcp + abase))[0], ((const float4*)(srcp + abase))[1]);
        a0[1] = cvt_frag(((const float4*)(dstp + abase))[0], ((const float4*)(dstp + abase))[1]);
        a0[2] = cvt_frag(((const float4*)(eap  + abase))[0], ((const float4*)(eap  + abase))[1]);
    }

    for (;;) {
        const int e0 = tile << 4;
        const int nt = tile + stride;

        // ---- prefetch next tile's x0 (consumed at loop end) ----
        const int pt = (nt < nTiles) ? nt : tile;
        const size_t pbase = (size_t)min((pt << 4) + n16, E - 1) * 32 + q * 8;
        float4 p0a = ((const float4*)(srcp + pbase))[0];
        float4 p0b = ((const float4*)(srcp + pbase))[1];
        float4 p1a = ((const float4*)(dstp + pbase))[0];
        float4 p1b = ((const float4*)(dstp + pbase))[1];
        float4 p2a = ((const float4*)(eap  + pbase))[0];
        float4 p2b = ((const float4*)(eap  + pbase))[1];

        // ---- GEMM1: [16x96] @ [96x64] ----
        f32x4 acc1[4] = {};
#pragma unroll
        for (int s = 0; s < 3; ++s)
#pragma unroll
            for (int t = 0; t < 4; ++t) {
                bf16x8 wf = *(const bf16x8*)(wl + (s * 4 + t) * 512);
                acc1[t] = __builtin_amdgcn_mfma_f32_16x16x32_bf16(a0[s], wf, acc1[t], 0, 0, 0);
            }

        ln_epilogue(acc1, b1v, g1v, e1v, h1p, n16, q);
        LDS_WAIT();

        // ---- GEMM2: [16x160] @ [160x64], A = [h1 | x0] ----
        f32x4 acc2[4] = {};
        bf16x8 h1f0 = ld_frag_lds8(h1p + n16 * HPAD + q * 8);
        bf16x8 h1f1 = ld_frag_lds8(h1p + n16 * HPAD + 32 + q * 8);
#pragma unroll
        for (int t = 0; t < 4; ++t) {
            bf16x8 wf = *(const bf16x8*)(wl + (12 + t) * 512);
            acc2[t] = __builtin_amdgcn_mfma_f32_16x16x32_bf16(h1f0, wf, acc2[t], 0, 0, 0);
        }
#pragma unroll
        for (int t = 0; t < 4; ++t) {
            bf16x8 wf = *(const bf16x8*)(wl + (16 + t) * 512);
            acc2[t] = __builtin_amdgcn_mfma_f32_16x16x32_bf16(h1f1, wf, acc2[t], 0, 0, 0);
        }
#pragma unroll
        for (int s = 0; s < 3; ++s)
#pragma unroll
            for (int t = 0; t < 4; ++t) {
                bf16x8 wf = *(const bf16x8*)(wl + (20 + s * 4 + t) * 512);
                acc2[t] = __builtin_amdgcn_mfma_f32_16x16x32_bf16(a0[s], wf, acc2[t], 0, 0, 0);
            }

        ln_epilogue(acc2, b2v, g2v, e2v, h2p, n16, q);
        LDS_WAIT();

        // ---- GEMM3: [16x64] @ [64x32] + b3 ----
        f32x4 acc3[2] = {};
#pragma unroll
        for (int s = 0; s < 2; ++s) {
            bf16x8 h2f = ld_frag_lds8(h2p + n16 * HPAD + s * 32 + q * 8);
#pragma unroll
            for (int t = 0; t < 2; ++t) {
                bf16x8 wf = *(const bf16x8*)(wl + (32 + s * 2 + t) * 512);
                acc3[t] = __builtin_amdgcn_mfma_f32_16x16x32_bf16(h2f, wf, acc3[t], 0, 0, 0);
            }
        }

        // store: lane holds out[e0 + 4q + j][t*16 + n16]
#pragma unroll
        for (int t = 0; t < 2; ++t)
#pragma unroll
            for (int j = 0; j < 4; ++j) {
                int r = e0 + q * 4 + j;
                if (r < E) out[(size_t)r * 32 + t * 16 + n16] = acc3[t][j] + b3v[t];
            }

        if (nt >= nTiles) break;
        tile = nt;
        a0[0] = cvt_frag(p0a, p0b);
        a0[1] = cvt_frag(p1a, p1b);
        a0[2] = cvt_frag(p2a, p2b);
    }
}

extern "C" void kernel_launch(void* const* d_in, const int* in_sizes, int n_in,
                              void* d_out, int out_size, void* d_ws, size_t ws_size,
                              hipStream_t stream) {
    (void)n_in; (void)out_size; (void)d_ws; (void)ws_size;
    const float* srcp = (const float*)d_in[0];
    const float* dstp = (const float*)d_in[1];
    const float* eap  = (const float*)d_in[2];
    const float* W1   = (const float*)d_in[3];
    const float* b1   = (const float*)d_in[4];
    const float* g1   = (const float*)d_in[5];
    const float* be1  = (const float*)d_in[6];
    const float* W2   = (const float*)d_in[7];
    const float* b2   = (const float*)d_in[8];
    const float* g2   = (const float*)d_in[9];
    const float* be2  = (const float*)d_in[10];
    const float* W3   = (const float*)d_in[11];
    const float* b3   = (const float*)d_in[12];
    float* out = (float*)d_out;

    const int E = in_sizes[0] / 32;
    const int nTiles = (E + 15) / 16;
    int blocks = (nTiles + NW - 1) / NW;
    if (blocks > 512) blocks = 512;  // 2 blocks/CU (LDS-limited), 16 waves/CU

    edge_model_kernel<<<blocks, 512, 0, stream>>>(srcp, dstp, eap, W1, b1, g1, be1,
                                                  W2, b2, g2, be2, W3, b3, out, E);
}